// Round 8
// baseline (238.235 us; speedup 1.0000x reference)
//
#include <hip/hip_runtime.h>
#include <math.h>

// Problem constants (fixed by the reference)
#define H_VAL   7500.0f
#define EH_VAL  750.0f          // 0.1f * 7500.0f, fp32-exact
#define N_DIM   64
#define T_DIM   65536
#define BLOCKS_PER_N 32
#define NBLOCKS (N_DIM * BLOCKS_PER_N)       // 2048 = 8 blocks/CU resident
#define THREADS 256
#define T_PER_BLOCK (T_DIM / BLOCKS_PER_N)   // 2048
#define ITERS (T_PER_BLOCK / THREADS)        // 8
#define BURST 4                              // 8 float4 loads in flight per burst
#define PART_OFF 16                          // floats; u32 ticket lives at ws[0]

__device__ __forceinline__ float dev_nan() { return __uint_as_float(0x7fc00000u); }
__device__ __forceinline__ bool is_nan(float x) { return x != x; }

// Statistics per (n,c), k = 0..6: {sum_all, sum_o, sum_u, sum_e, cnt_o, cnt_u, cnt_e}
// FUSED partial layout (transposed for coalesced finalize gather):
//   ws[PART_OFF + (c*7+k)*NBLOCKS + block]
// Ticket at ws[0], zeroed by a 16-byte memsetAsync each call -> winner is the
// LAST block to arrive (old == NBLOCKS-1), after all partials are fenced.
// Fallback atomic layout: ws[n*32 + c*8 + (0..3 sums | 4..6 counts)], memset first.

template <bool FUSED>
__global__ __launch_bounds__(THREADS) void mae_stage1(
        const float* __restrict__ outp, const float* __restrict__ tgtp,
        float* __restrict__ ws, float* __restrict__ outv) {
    const int bid = blockIdx.x;
    const int n = bid / BLOCKS_PER_N;
    const int slice = bid % BLOCKS_PER_N;
    const int t0 = slice * T_PER_BLOCK;
    const int tid = threadIdx.x;
    const int lane = tid & 63;
    const float h = H_VAL;
    const float eh = EH_VAL;

    // 16 per-lane float sums: w[c*4 + {0:all,1:o,2:u,3:e}]
    float w[16];
    #pragma unroll
    for (int i = 0; i < 16; ++i) w[i] = 0.0f;
    // 4 packed u32 counters/lane: bits 0-9 cnt_o, 10-19 cnt_u, 20-29 cnt_e
    unsigned cnt[4] = {0u, 0u, 0u, 0u};

    const float4* o4 = reinterpret_cast<const float4*>(outp) + (size_t)n * T_DIM;
    const float4* t4 = reinterpret_cast<const float4*>(tgtp) + (size_t)n * T_DIM;

    // Burst-4: 8 independent 16B loads in program order before any use (MLP=8).
    #pragma unroll
    for (int half = 0; half < ITERS / BURST; ++half) {
        float4 lo[BURST], lt[BURST];
        #pragma unroll
        for (int j = 0; j < BURST; ++j)
            lo[j] = o4[t0 + (half * BURST + j) * THREADS + tid];
        #pragma unroll
        for (int j = 0; j < BURST; ++j)
            lt[j] = t4[t0 + (half * BURST + j) * THREADS + tid];

        #pragma unroll
        for (int j = 0; j < BURST; ++j) {
            const float os[4] = {lo[j].x, lo[j].y, lo[j].z, lo[j].w};
            const float ts[4] = {lt[j].x, lt[j].y, lt[j].z, lt[j].w};
            #pragma unroll
            for (int c = 0; c < 4; ++c) {
                const float traw = ts[c];
                const bool bo = (traw >= h) || (traw < 0.0f);  // == (tc==h)
                const float tc = bo ? h : traw;
                const float d = fabsf(os[c] - tc);
                const bool bu = (traw == 0.0f);
                const bool be = (traw > 0.0f) && (traw < eh);
                w[c * 4 + 0] += d;
                w[c * 4 + 1] += bo ? d : 0.0f;
                w[c * 4 + 2] += bu ? d : 0.0f;
                w[c * 4 + 3] += be ? d : 0.0f;
                cnt[c] += (bo ? 1u : 0u) + (bu ? (1u << 10) : 0u) + (be ? (1u << 20) : 0u);
            }
        }
    }

    // --- Split-butterfly: 16 sums across 64 lanes in 17 shuffles ---
    #pragma unroll
    for (int r = 0; r < 4; ++r) {
        const int dist = 1 << r;
        const bool hi = (lane >> r) & 1;
        const int c16 = 8 >> r;
        #pragma unroll
        for (int j = 0; j < c16; ++j) {
            const float send = hi ? w[j] : w[j + c16];
            const float recv = __shfl_xor(send, dist, 64);
            w[j] = (hi ? w[j + c16] : w[j]) + recv;
        }
    }
    w[0] += __shfl_xor(w[0], 16, 64);
    w[0] += __shfl_xor(w[0], 32, 64);
    const int l4 = lane & 15;
    const int slot = ((l4 & 1) << 3) | (((l4 >> 1) & 1) << 2) |
                     (((l4 >> 2) & 1) << 1) | ((l4 >> 3) & 1);

    // --- Packed counts: 4 slots across 64 lanes in 7 shuffles ---
    #pragma unroll
    for (int r = 0; r < 2; ++r) {
        const int dist = 1 << r;
        const bool hi = (lane >> r) & 1;
        const int c4 = 2 >> r;
        #pragma unroll
        for (int j = 0; j < c4; ++j) {
            const unsigned send = hi ? cnt[j] : cnt[j + c4];
            const unsigned recv = __shfl_xor(send, dist, 64);
            cnt[j] = (hi ? cnt[j + c4] : cnt[j]) + recv;
        }
    }
    cnt[0] += __shfl_xor(cnt[0], 4, 64);
    cnt[0] += __shfl_xor(cnt[0], 8, 64);
    cnt[0] += __shfl_xor(cnt[0], 16, 64);
    cnt[0] += __shfl_xor(cnt[0], 32, 64);
    const int slot2 = ((lane & 1) << 1) | ((lane >> 1) & 1);

    __shared__ float    lsum[4][16];
    __shared__ unsigned lcnt[4][4];
    const int wave = tid >> 6;
    if (lane < 16) lsum[wave][slot] = w[0];
    if (lane < 4)  lcnt[wave][slot2] = cnt[0];
    __syncthreads();

    if (tid < 16) {
        const float s = lsum[0][tid] + lsum[1][tid] + lsum[2][tid] + lsum[3][tid];
        const int c = tid >> 2, k = tid & 3;
        if (FUSED) ws[PART_OFF + (c * 7 + k) * NBLOCKS + bid] = s;
        else       atomicAdd(&ws[n * 32 + c * 8 + k], s);
    } else if (tid < 28) {
        const int j = tid - 16, f = j >> 2, c = j & 3;
        const unsigned v = ((lcnt[0][c] >> (10 * f)) & 1023u) +
                           ((lcnt[1][c] >> (10 * f)) & 1023u) +
                           ((lcnt[2][c] >> (10 * f)) & 1023u) +
                           ((lcnt[3][c] >> (10 * f)) & 1023u);
        const float fv = (float)v;
        if (FUSED) ws[PART_OFF + (c * 7 + 4 + f) * NBLOCKS + bid] = fv;
        else       atomicAdd(&ws[n * 32 + c * 8 + 4 + f], fv);
    }

    if (!FUSED) return;

    // --- Last-block-finalizes. Canonical pattern: every writer fences its own
    // stores (threadfence only orders the CALLING thread's ops), block barrier,
    // then the leader takes a ticket. Ticket starts at 0 (memset each call), so
    // the winner (old == NBLOCKS-1) is the LAST arrival: all partials fenced. ---
    __threadfence();                      // release, executed by ALL threads
    __syncthreads();
    __shared__ unsigned last;
    if (tid == 0) last = atomicAdd((unsigned*)ws, 1u);
    __syncthreads();
    if (last != (unsigned)(NBLOCKS - 1)) return;

    __threadfence();                      // acquire: see all blocks' partials

    // --- Finalize: thread i = (n,c); gather 7 stats x 32 blocks (float4 rows) ---
    const int fn = tid >> 2, fc = tid & 3;
    float a[7];
    #pragma unroll 1
    for (int k = 0; k < 7; ++k) {         // unroll 1: keep VGPR below main loop's
        const float4* p = reinterpret_cast<const float4*>(
            ws + PART_OFF + (size_t)(fc * 7 + k) * NBLOCKS + fn * BLOCKS_PER_N);
        float s = 0.0f;
        #pragma unroll
        for (int q = 0; q < 8; ++q) {     // 8 independent 16B loads
            const float4 v = p[q];
            s += (v.x + v.y) + (v.z + v.w);
        }
        a[k] = s;
    }

    const float sum_all = a[0], sum_o = a[1], sum_u = a[2], sum_e = a[3];
    const float cnt_o = a[4], cnt_u = a[5], cnt_e = a[6];
    const float cnt_in = (float)T_DIM - cnt_o - cnt_u;   // exact in fp32
    const float sum_in = sum_all - sum_o - sum_u;

    const float m_o  = (cnt_o  > 0.0f) ? sum_o  / cnt_o  : dev_nan();
    const float m_in = (cnt_in > 0.0f) ? sum_in / cnt_in : dev_nan();
    const float m_u  = (cnt_u  > 0.0f) ? sum_u  / cnt_u  : dev_nan();
    const float m_e  = (cnt_e  > 0.0f) ? sum_e  / cnt_e  : dev_nan();

    auto nm2 = [](float x, float y) {
        const bool vx = !is_nan(x), vy = !is_nan(y);
        const float s  = (vx ? x : 0.0f) + (vy ? y : 0.0f);
        const float cc = (vx ? 1.0f : 0.0f) + (vy ? 1.0f : 0.0f);
        return (cc > 0.0f) ? s / cc : dev_nan();
    };
    const float in_comb = nm2(m_u, m_in);
    const float wv      = nm2(m_o, in_comb);

    float vals[4] = {wv, in_comb, m_o, m_e};   // -> wMAE, inMAE, oMAE, eMAE
    float sums[4], cnts[4];
    #pragma unroll
    for (int j = 0; j < 4; ++j) {
        const bool valid = !is_nan(vals[j]);
        sums[j] = valid ? vals[j] : 0.0f;
        cnts[j] = valid ? 1.0f : 0.0f;
    }
    #pragma unroll
    for (int j = 0; j < 4; ++j) {
        #pragma unroll
        for (int off = 32; off > 0; off >>= 1) {
            sums[j] += __shfl_down(sums[j], off, 64);
            cnts[j] += __shfl_down(cnts[j], off, 64);
        }
    }
    __shared__ float ls[4][8];
    if (lane == 0) {
        #pragma unroll
        for (int j = 0; j < 4; ++j) { ls[wave][j] = sums[j]; ls[wave][j + 4] = cnts[j]; }
    }
    __syncthreads();
    if (tid == 0) {
        #pragma unroll
        for (int j = 0; j < 4; ++j) {
            const float s  = ls[0][j] + ls[1][j] + ls[2][j] + ls[3][j];
            const float cc = ls[0][j + 4] + ls[1][j + 4] + ls[2][j + 4] + ls[3][j + 4];
            outv[j] = (cc > 0.0f) ? s / cc : dev_nan();
        }
    }
}

// Fallback-only finalize kernel (atomic layout), used when ws is tiny.
__global__ __launch_bounds__(256) void mae_stage2(
        const float* __restrict__ ws, float* __restrict__ outp) {
    const int i = threadIdx.x;            // 0..255 == (n,c) pair
    const int n = i >> 2, c = i & 3;
    const float* p = &ws[n * 32 + c * 8];
    float a[7];
    #pragma unroll
    for (int k = 0; k < 7; ++k) a[k] = p[k];

    const float sum_all = a[0], sum_o = a[1], sum_u = a[2], sum_e = a[3];
    const float cnt_o = a[4], cnt_u = a[5], cnt_e = a[6];
    const float cnt_in = (float)T_DIM - cnt_o - cnt_u;
    const float sum_in = sum_all - sum_o - sum_u;

    const float m_o  = (cnt_o  > 0.0f) ? sum_o  / cnt_o  : dev_nan();
    const float m_in = (cnt_in > 0.0f) ? sum_in / cnt_in : dev_nan();
    const float m_u  = (cnt_u  > 0.0f) ? sum_u  / cnt_u  : dev_nan();
    const float m_e  = (cnt_e  > 0.0f) ? sum_e  / cnt_e  : dev_nan();

    auto nm2 = [](float x, float y) {
        const bool vx = !is_nan(x), vy = !is_nan(y);
        const float s  = (vx ? x : 0.0f) + (vy ? y : 0.0f);
        const float cc = (vx ? 1.0f : 0.0f) + (vy ? 1.0f : 0.0f);
        return (cc > 0.0f) ? s / cc : dev_nan();
    };
    const float in_comb = nm2(m_u, m_in);
    const float wv      = nm2(m_o, in_comb);

    float vals[4] = {wv, in_comb, m_o, m_e};
    float sums[4], cnts[4];
    #pragma unroll
    for (int j = 0; j < 4; ++j) {
        const bool valid = !is_nan(vals[j]);
        sums[j] = valid ? vals[j] : 0.0f;
        cnts[j] = valid ? 1.0f : 0.0f;
    }
    #pragma unroll
    for (int j = 0; j < 4; ++j) {
        #pragma unroll
        for (int off = 32; off > 0; off >>= 1) {
            sums[j] += __shfl_down(sums[j], off, 64);
            cnts[j] += __shfl_down(cnts[j], off, 64);
        }
    }
    __shared__ float ls[4][8];
    const int wave = threadIdx.x >> 6;
    const int lane = threadIdx.x & 63;
    if (lane == 0) {
        #pragma unroll
        for (int j = 0; j < 4; ++j) { ls[wave][j] = sums[j]; ls[wave][j + 4] = cnts[j]; }
    }
    __syncthreads();
    if (threadIdx.x == 0) {
        #pragma unroll
        for (int j = 0; j < 4; ++j) {
            const float s  = ls[0][j] + ls[1][j] + ls[2][j] + ls[3][j];
            const float cc = ls[0][j + 4] + ls[1][j + 4] + ls[2][j + 4] + ls[3][j + 4];
            outp[j] = (cc > 0.0f) ? s / cc : dev_nan();
        }
    }
}

extern "C" void kernel_launch(void* const* d_in, const int* in_sizes, int n_in,
                              void* d_out, int out_size, void* d_ws, size_t ws_size,
                              hipStream_t stream) {
    const float* out_rsd = (const float*)d_in[0];
    const float* tgt_rsd = (const float*)d_in[1];
    float* outv = (float*)d_out;
    float* ws = (float*)d_ws;

    const size_t fused_bytes = (size_t)(PART_OFF + 28 * NBLOCKS) * sizeof(float);
    if (ws_size >= fused_bytes) {
        // Zero the 16-byte ticket region only; partials are stored unconditionally.
        hipMemsetAsync(ws, 0, 16, stream);
        mae_stage1<true><<<NBLOCKS, THREADS, 0, stream>>>(out_rsd, tgt_rsd, ws, outv);
    } else {
        // Fallback: 8 KB accumulator + atomics + separate finalize kernel.
        hipMemsetAsync(ws, 0, N_DIM * 32 * sizeof(float), stream);
        mae_stage1<false><<<NBLOCKS, THREADS, 0, stream>>>(out_rsd, tgt_rsd, ws, outv);
        mae_stage2<<<1, 256, 0, stream>>>(ws, outv);
    }
}

// Round 9
// 40.352 us; speedup vs baseline: 5.9040x; 5.9040x over previous
//
#include <hip/hip_runtime.h>
#include <math.h>

// Problem constants (fixed by the reference)
#define H_VAL   7500.0f
#define EH_VAL  750.0f          // 0.1f * 7500.0f, fp32-exact
#define N_DIM   64
#define T_DIM   65536
#define BLOCKS_PER_N 32
#define NBLOCKS (N_DIM * BLOCKS_PER_N)       // 2048 = 8 blocks/CU resident
#define THREADS 256
#define T_PER_BLOCK (T_DIM / BLOCKS_PER_N)   // 2048
#define ITERS (T_PER_BLOCK / THREADS)        // 8
#define BURST 4                              // 8 float4 loads in flight per burst

__device__ __forceinline__ float dev_nan() { return __uint_as_float(0x7fc00000u); }
__device__ __forceinline__ bool is_nan(float x) { return x != x; }

// Statistics per (n,c), k = 0..6: {sum_all, sum_o, sum_u, sum_e, cnt_o, cnt_u, cnt_e}
// Partials mode: ws[block*28 + (0..15 sums: c*4+k | 16..27 counts: 16+f*4+c)]
// Atomic fallback: ws[n*32 + c*8 + (0..3 sums | 4..6 counts)], memset first.

template <bool ATOMIC>
__global__ __launch_bounds__(THREADS) void mae_stage1(
        const float* __restrict__ outp, const float* __restrict__ tgtp,
        float* __restrict__ ws) {
    const int bid = blockIdx.x;
    const int n = bid / BLOCKS_PER_N;
    const int slice = bid % BLOCKS_PER_N;
    const int t0 = slice * T_PER_BLOCK;
    const int tid = threadIdx.x;
    const int lane = tid & 63;
    const float h = H_VAL;
    const float eh = EH_VAL;

    // 16 per-lane float sums: w[c*4 + {0:all,1:o,2:u,3:e}]
    float w[16];
    #pragma unroll
    for (int i = 0; i < 16; ++i) w[i] = 0.0f;
    // 4 packed u32 counters/lane: bits 0-9 cnt_o, 10-19 cnt_u, 20-29 cnt_e
    unsigned cnt[4] = {0u, 0u, 0u, 0u};

    const float4* o4 = reinterpret_cast<const float4*>(outp) + (size_t)n * T_DIM;
    const float4* t4 = reinterpret_cast<const float4*>(tgtp) + (size_t)n * T_DIM;

    // Burst-4: 8 independent 16B loads in program order before any use (MLP=8).
    #pragma unroll
    for (int half = 0; half < ITERS / BURST; ++half) {
        float4 lo[BURST], lt[BURST];
        #pragma unroll
        for (int j = 0; j < BURST; ++j)
            lo[j] = o4[t0 + (half * BURST + j) * THREADS + tid];
        #pragma unroll
        for (int j = 0; j < BURST; ++j)
            lt[j] = t4[t0 + (half * BURST + j) * THREADS + tid];

        #pragma unroll
        for (int j = 0; j < BURST; ++j) {
            const float os[4] = {lo[j].x, lo[j].y, lo[j].z, lo[j].w};
            const float ts[4] = {lt[j].x, lt[j].y, lt[j].z, lt[j].w};
            #pragma unroll
            for (int c = 0; c < 4; ++c) {
                const float traw = ts[c];
                const bool bo = (traw >= h) || (traw < 0.0f);  // == (tc==h)
                const float tc = bo ? h : traw;
                const float d = fabsf(os[c] - tc);
                const bool bu = (traw == 0.0f);
                const bool be = (traw > 0.0f) && (traw < eh);
                w[c * 4 + 0] += d;
                w[c * 4 + 1] += bo ? d : 0.0f;
                w[c * 4 + 2] += bu ? d : 0.0f;
                w[c * 4 + 3] += be ? d : 0.0f;
                cnt[c] += (bo ? 1u : 0u) + (bu ? (1u << 10) : 0u) + (be ? (1u << 20) : 0u);
            }
        }
    }

    // --- Split-butterfly: 16 sums across 64 lanes in 17 shuffles ---
    #pragma unroll
    for (int r = 0; r < 4; ++r) {
        const int dist = 1 << r;
        const bool hi = (lane >> r) & 1;
        const int c16 = 8 >> r;
        #pragma unroll
        for (int j = 0; j < c16; ++j) {
            const float send = hi ? w[j] : w[j + c16];
            const float recv = __shfl_xor(send, dist, 64);
            w[j] = (hi ? w[j + c16] : w[j]) + recv;
        }
    }
    w[0] += __shfl_xor(w[0], 16, 64);
    w[0] += __shfl_xor(w[0], 32, 64);
    const int l4 = lane & 15;
    const int slot = ((l4 & 1) << 3) | (((l4 >> 1) & 1) << 2) |
                     (((l4 >> 2) & 1) << 1) | ((l4 >> 3) & 1);

    // --- Packed counts: 4 slots across 64 lanes in 7 shuffles ---
    #pragma unroll
    for (int r = 0; r < 2; ++r) {
        const int dist = 1 << r;
        const bool hi = (lane >> r) & 1;
        const int c4 = 2 >> r;
        #pragma unroll
        for (int j = 0; j < c4; ++j) {
            const unsigned send = hi ? cnt[j] : cnt[j + c4];
            const unsigned recv = __shfl_xor(send, dist, 64);
            cnt[j] = (hi ? cnt[j + c4] : cnt[j]) + recv;
        }
    }
    cnt[0] += __shfl_xor(cnt[0], 4, 64);
    cnt[0] += __shfl_xor(cnt[0], 8, 64);
    cnt[0] += __shfl_xor(cnt[0], 16, 64);
    cnt[0] += __shfl_xor(cnt[0], 32, 64);
    const int slot2 = ((lane & 1) << 1) | ((lane >> 1) & 1);

    __shared__ float    lsum[4][16];
    __shared__ unsigned lcnt[4][4];
    const int wave = tid >> 6;
    if (lane < 16) lsum[wave][slot] = w[0];
    if (lane < 4)  lcnt[wave][slot2] = cnt[0];
    __syncthreads();

    if (tid < 16) {
        const float s = lsum[0][tid] + lsum[1][tid] + lsum[2][tid] + lsum[3][tid];
        const int c = tid >> 2, k = tid & 3;
        if (ATOMIC) atomicAdd(&ws[n * 32 + c * 8 + k], s);
        else        ws[bid * 28 + tid] = s;
    } else if (tid < 28) {
        const int j = tid - 16, f = j >> 2, c = j & 3;
        const unsigned v = ((lcnt[0][c] >> (10 * f)) & 1023u) +
                           ((lcnt[1][c] >> (10 * f)) & 1023u) +
                           ((lcnt[2][c] >> (10 * f)) & 1023u) +
                           ((lcnt[3][c] >> (10 * f)) & 1023u);
        const float fv = (float)v;
        if (ATOMIC) atomicAdd(&ws[n * 32 + c * 8 + 4 + f], fv);
        else        ws[bid * 28 + tid] = fv;
    }
}

template <bool ATOMIC>
__global__ __launch_bounds__(256) void mae_stage2(
        const float* __restrict__ ws, float* __restrict__ outp) {
    const int i = threadIdx.x;            // 0..255 == (n,c) pair
    const int n = i >> 2, c = i & 3;

    float a[7];
    if (ATOMIC) {
        const float* p = &ws[n * 32 + c * 8];
        #pragma unroll
        for (int k = 0; k < 7; ++k) a[k] = p[k];
    } else {
        #pragma unroll
        for (int k = 0; k < 7; ++k) a[k] = 0.0f;
        for (int s = 0; s < BLOCKS_PER_N; ++s) {
            const float* p = &ws[(size_t)(n * BLOCKS_PER_N + s) * 28];
            #pragma unroll
            for (int k = 0; k < 4; ++k) a[k] += p[c * 4 + k];
            #pragma unroll
            for (int f = 0; f < 3; ++f) a[4 + f] += p[16 + f * 4 + c];
        }
    }

    const float sum_all = a[0], sum_o = a[1], sum_u = a[2], sum_e = a[3];
    const float cnt_o = a[4], cnt_u = a[5], cnt_e = a[6];
    const float cnt_in = (float)T_DIM - cnt_o - cnt_u;   // exact in fp32
    const float sum_in = sum_all - sum_o - sum_u;

    const float m_o  = (cnt_o  > 0.0f) ? sum_o  / cnt_o  : dev_nan();
    const float m_in = (cnt_in > 0.0f) ? sum_in / cnt_in : dev_nan();
    const float m_u  = (cnt_u  > 0.0f) ? sum_u  / cnt_u  : dev_nan();
    const float m_e  = (cnt_e  > 0.0f) ? sum_e  / cnt_e  : dev_nan();

    auto nm2 = [](float x, float y) {
        const bool vx = !is_nan(x), vy = !is_nan(y);
        const float s  = (vx ? x : 0.0f) + (vy ? y : 0.0f);
        const float cc = (vx ? 1.0f : 0.0f) + (vy ? 1.0f : 0.0f);
        return (cc > 0.0f) ? s / cc : dev_nan();
    };
    const float in_comb = nm2(m_u, m_in);
    const float wv      = nm2(m_o, in_comb);

    float vals[4] = {wv, in_comb, m_o, m_e};   // -> wMAE, inMAE, oMAE, eMAE
    float sums[4], cnts[4];
    #pragma unroll
    for (int j = 0; j < 4; ++j) {
        const bool valid = !is_nan(vals[j]);
        sums[j] = valid ? vals[j] : 0.0f;
        cnts[j] = valid ? 1.0f : 0.0f;
    }
    #pragma unroll
    for (int j = 0; j < 4; ++j) {
        #pragma unroll
        for (int off = 32; off > 0; off >>= 1) {
            sums[j] += __shfl_down(sums[j], off, 64);
            cnts[j] += __shfl_down(cnts[j], off, 64);
        }
    }
    __shared__ float ls[4][8];
    const int wave = threadIdx.x >> 6;
    const int lane = threadIdx.x & 63;
    if (lane == 0) {
        #pragma unroll
        for (int j = 0; j < 4; ++j) { ls[wave][j] = sums[j]; ls[wave][j + 4] = cnts[j]; }
    }
    __syncthreads();
    if (threadIdx.x == 0) {
        #pragma unroll
        for (int j = 0; j < 4; ++j) {
            const float s  = ls[0][j] + ls[1][j] + ls[2][j] + ls[3][j];
            const float cc = ls[0][j + 4] + ls[1][j + 4] + ls[2][j + 4] + ls[3][j + 4];
            outp[j] = (cc > 0.0f) ? s / cc : dev_nan();
        }
    }
}

extern "C" void kernel_launch(void* const* d_in, const int* in_sizes, int n_in,
                              void* d_out, int out_size, void* d_ws, size_t ws_size,
                              hipStream_t stream) {
    const float* out_rsd = (const float*)d_in[0];
    const float* tgt_rsd = (const float*)d_in[1];
    float* outv = (float*)d_out;
    float* ws = (float*)d_ws;

    const size_t partials_bytes = (size_t)NBLOCKS * 28 * sizeof(float);
    if (ws_size >= partials_bytes) {
        // No memset, no atomics: every partial slot is written unconditionally.
        mae_stage1<false><<<NBLOCKS, THREADS, 0, stream>>>(out_rsd, tgt_rsd, ws);
        mae_stage2<false><<<1, 256, 0, stream>>>(ws, outv);
    } else {
        // Fallback: 8 KB accumulator + atomics (deterministic; ws_size is fixed).
        hipMemsetAsync(ws, 0, N_DIM * 32 * sizeof(float), stream);
        mae_stage1<true><<<NBLOCKS, THREADS, 0, stream>>>(out_rsd, tgt_rsd, ws);
        mae_stage2<true><<<1, 256, 0, stream>>>(ws, outv);
    }
}

// Round 10
// 35.456 us; speedup vs baseline: 6.7191x; 1.1381x over previous
//
#include <hip/hip_runtime.h>
#include <math.h>

// Problem constants (fixed by the reference)
#define H_VAL   7500.0f
#define EH_VAL  750.0f          // 0.1f * 7500.0f, fp32-exact
#define N_DIM   64
#define T_DIM   65536
#define BLOCKS_PER_N 32
#define NBLOCKS (N_DIM * BLOCKS_PER_N)       // 2048 = 8 blocks/CU resident
#define THREADS 256
#define T_PER_BLOCK (T_DIM / BLOCKS_PER_N)   // 2048
#define ITERS (T_PER_BLOCK / THREADS)        // 8

__device__ __forceinline__ float dev_nan() { return __uint_as_float(0x7fc00000u); }
__device__ __forceinline__ bool is_nan(float x) { return x != x; }

// Statistics per (n,c), k = 0..6: {sum_all, sum_o, sum_u, sum_e, cnt_o, cnt_u, cnt_e}
// Partials (transposed for coalesced stage2 bursts): ws[(c*7+k)*NBLOCKS + bid]
//   -> the 32 blocks of one n are CONSECUTIVE floats within a row.
// Atomic fallback: ws[n*32 + c*8 + (0..3 sums | 4..6 counts)], memset first.

template <bool ATOMIC>
__global__ __launch_bounds__(THREADS) void mae_stage1(
        const float* __restrict__ outp, const float* __restrict__ tgtp,
        float* __restrict__ ws) {
    const int bid = blockIdx.x;
    const int n = bid / BLOCKS_PER_N;
    const int slice = bid % BLOCKS_PER_N;
    const int t0 = slice * T_PER_BLOCK;
    const int tid = threadIdx.x;
    const int lane = tid & 63;
    const float h = H_VAL;
    const float eh = EH_VAL;

    // 16 per-lane float sums: w[c*4 + {0:all,1:o,2:u,3:e}]
    float w[16];
    #pragma unroll
    for (int i = 0; i < 16; ++i) w[i] = 0.0f;
    // 4 packed u32 counters/lane: bits 0-9 cnt_o, 10-19 cnt_u, 20-29 cnt_e
    unsigned cnt[4] = {0u, 0u, 0u, 0u};

    const float4* o4 = reinterpret_cast<const float4*>(outp) + (size_t)n * T_DIM;
    const float4* t4 = reinterpret_cast<const float4*>(tgtp) + (size_t)n * T_DIM;

    auto proc = [&](const float4& ov, const float4& tv) {
        const float os[4] = {ov.x, ov.y, ov.z, ov.w};
        const float ts[4] = {tv.x, tv.y, tv.z, tv.w};
        #pragma unroll
        for (int c = 0; c < 4; ++c) {
            const float traw = ts[c];
            const bool bo = (traw >= h) || (traw < 0.0f);  // == (tc==h)
            const float tc = bo ? h : traw;
            const float d = fabsf(os[c] - tc);
            const bool bu = (traw == 0.0f);
            const bool be = (traw > 0.0f) && (traw < eh);
            w[c * 4 + 0] += d;
            w[c * 4 + 1] += bo ? d : 0.0f;
            w[c * 4 + 2] += bu ? d : 0.0f;
            w[c * 4 + 3] += be ? d : 0.0f;
            cnt[c] += (bo ? 1u : 0u) + (bu ? (1u << 10) : 0u) + (be ? (1u << 20) : 0u);
        }
    };

#define IDX(i) ((size_t)(t0 + (i) * THREADS + tid))
    // R4-proven loop shape (compiles lean: VGPR 32, VALUBusy ~19%).
    float4 a0o = o4[IDX(0)], a1o = o4[IDX(1)];
    float4 a0t = t4[IDX(0)], a1t = t4[IDX(1)];
    #pragma unroll
    for (int it = 0; it < ITERS; it += 2) {
        float4 b0o = a0o, b1o = a1o, b0t = a0t, b1t = a1t;
        if (it + 2 < ITERS) {
            b0o = o4[IDX(it + 2)]; b1o = o4[IDX(it + 3)];
            b0t = t4[IDX(it + 2)]; b1t = t4[IDX(it + 3)];
        }
        proc(a0o, a0t);
        proc(a1o, a1t);
        a0o = b0o; a1o = b1o; a0t = b0t; a1t = b1t;
    }
#undef IDX

    // --- Split-butterfly: 16 sums across 64 lanes in 17 shuffles ---
    #pragma unroll
    for (int r = 0; r < 4; ++r) {
        const int dist = 1 << r;
        const bool hi = (lane >> r) & 1;
        const int c16 = 8 >> r;
        #pragma unroll
        for (int j = 0; j < c16; ++j) {
            const float send = hi ? w[j] : w[j + c16];
            const float recv = __shfl_xor(send, dist, 64);
            w[j] = (hi ? w[j + c16] : w[j]) + recv;
        }
    }
    w[0] += __shfl_xor(w[0], 16, 64);
    w[0] += __shfl_xor(w[0], 32, 64);
    const int l4 = lane & 15;
    const int slot = ((l4 & 1) << 3) | (((l4 >> 1) & 1) << 2) |
                     (((l4 >> 2) & 1) << 1) | ((l4 >> 3) & 1);

    // --- Packed counts: 4 slots across 64 lanes in 7 shuffles ---
    #pragma unroll
    for (int r = 0; r < 2; ++r) {
        const int dist = 1 << r;
        const bool hi = (lane >> r) & 1;
        const int c4 = 2 >> r;
        #pragma unroll
        for (int j = 0; j < c4; ++j) {
            const unsigned send = hi ? cnt[j] : cnt[j + c4];
            const unsigned recv = __shfl_xor(send, dist, 64);
            cnt[j] = (hi ? cnt[j + c4] : cnt[j]) + recv;
        }
    }
    cnt[0] += __shfl_xor(cnt[0], 4, 64);
    cnt[0] += __shfl_xor(cnt[0], 8, 64);
    cnt[0] += __shfl_xor(cnt[0], 16, 64);
    cnt[0] += __shfl_xor(cnt[0], 32, 64);
    const int slot2 = ((lane & 1) << 1) | ((lane >> 1) & 1);

    __shared__ float    lsum[4][16];
    __shared__ unsigned lcnt[4][4];
    const int wave = tid >> 6;
    if (lane < 16) lsum[wave][slot] = w[0];
    if (lane < 4)  lcnt[wave][slot2] = cnt[0];
    __syncthreads();

    if (tid < 16) {
        const float s = lsum[0][tid] + lsum[1][tid] + lsum[2][tid] + lsum[3][tid];
        const int c = tid >> 2, k = tid & 3;
        if (ATOMIC) atomicAdd(&ws[n * 32 + c * 8 + k], s);
        else        ws[(size_t)(c * 7 + k) * NBLOCKS + bid] = s;
    } else if (tid < 28) {
        const int j = tid - 16, f = j >> 2, c = j & 3;
        const unsigned v = ((lcnt[0][c] >> (10 * f)) & 1023u) +
                           ((lcnt[1][c] >> (10 * f)) & 1023u) +
                           ((lcnt[2][c] >> (10 * f)) & 1023u) +
                           ((lcnt[3][c] >> (10 * f)) & 1023u);
        const float fv = (float)v;
        if (ATOMIC) atomicAdd(&ws[n * 32 + c * 8 + 4 + f], fv);
        else        ws[(size_t)(c * 7 + 4 + f) * NBLOCKS + bid] = fv;
    }
}

template <bool ATOMIC>
__global__ __launch_bounds__(256) void mae_stage2(
        const float* __restrict__ ws, float* __restrict__ outp) {
    const int i = threadIdx.x;            // 0..255 == (n,c) pair
    const int n = i >> 2, c = i & 3;

    float a[7];
    if (ATOMIC) {
        const float* p = &ws[n * 32 + c * 8];
        #pragma unroll
        for (int k = 0; k < 7; ++k) a[k] = p[k];
    } else {
        // Transposed partials: row (c*7+k), 32 consecutive floats at n*32.
        // 7 x 8 independent float4 loads per thread - burstable, L2-hot.
        #pragma unroll
        for (int k = 0; k < 7; ++k) {
            const float4* p = reinterpret_cast<const float4*>(
                ws + (size_t)(c * 7 + k) * NBLOCKS + n * BLOCKS_PER_N);
            float4 v[8];
            #pragma unroll
            for (int q = 0; q < 8; ++q) v[q] = p[q];
            float s = 0.0f;
            #pragma unroll
            for (int q = 0; q < 8; ++q) s += (v[q].x + v[q].y) + (v[q].z + v[q].w);
            a[k] = s;
        }
    }

    const float sum_all = a[0], sum_o = a[1], sum_u = a[2], sum_e = a[3];
    const float cnt_o = a[4], cnt_u = a[5], cnt_e = a[6];
    const float cnt_in = (float)T_DIM - cnt_o - cnt_u;   // exact in fp32
    const float sum_in = sum_all - sum_o - sum_u;

    const float m_o  = (cnt_o  > 0.0f) ? sum_o  / cnt_o  : dev_nan();
    const float m_in = (cnt_in > 0.0f) ? sum_in / cnt_in : dev_nan();
    const float m_u  = (cnt_u  > 0.0f) ? sum_u  / cnt_u  : dev_nan();
    const float m_e  = (cnt_e  > 0.0f) ? sum_e  / cnt_e  : dev_nan();

    auto nm2 = [](float x, float y) {
        const bool vx = !is_nan(x), vy = !is_nan(y);
        const float s  = (vx ? x : 0.0f) + (vy ? y : 0.0f);
        const float cc = (vx ? 1.0f : 0.0f) + (vy ? 1.0f : 0.0f);
        return (cc > 0.0f) ? s / cc : dev_nan();
    };
    const float in_comb = nm2(m_u, m_in);
    const float wv      = nm2(m_o, in_comb);

    float vals[4] = {wv, in_comb, m_o, m_e};   // -> wMAE, inMAE, oMAE, eMAE
    float sums[4], cnts[4];
    #pragma unroll
    for (int j = 0; j < 4; ++j) {
        const bool valid = !is_nan(vals[j]);
        sums[j] = valid ? vals[j] : 0.0f;
        cnts[j] = valid ? 1.0f : 0.0f;
    }
    #pragma unroll
    for (int j = 0; j < 4; ++j) {
        #pragma unroll
        for (int off = 32; off > 0; off >>= 1) {
            sums[j] += __shfl_down(sums[j], off, 64);
            cnts[j] += __shfl_down(cnts[j], off, 64);
        }
    }
    __shared__ float ls[4][8];
    const int wave = threadIdx.x >> 6;
    const int lane = threadIdx.x & 63;
    if (lane == 0) {
        #pragma unroll
        for (int j = 0; j < 4; ++j) { ls[wave][j] = sums[j]; ls[wave][j + 4] = cnts[j]; }
    }
    __syncthreads();
    if (threadIdx.x == 0) {
        #pragma unroll
        for (int j = 0; j < 4; ++j) {
            const float s  = ls[0][j] + ls[1][j] + ls[2][j] + ls[3][j];
            const float cc = ls[0][j + 4] + ls[1][j + 4] + ls[2][j + 4] + ls[3][j + 4];
            outp[j] = (cc > 0.0f) ? s / cc : dev_nan();
        }
    }
}

extern "C" void kernel_launch(void* const* d_in, const int* in_sizes, int n_in,
                              void* d_out, int out_size, void* d_ws, size_t ws_size,
                              hipStream_t stream) {
    const float* out_rsd = (const float*)d_in[0];
    const float* tgt_rsd = (const float*)d_in[1];
    float* outv = (float*)d_out;
    float* ws = (float*)d_ws;

    const size_t partials_bytes = (size_t)NBLOCKS * 28 * sizeof(float);
    if (ws_size >= partials_bytes) {
        // No memset, no atomics: every partial slot is written unconditionally.
        mae_stage1<false><<<NBLOCKS, THREADS, 0, stream>>>(out_rsd, tgt_rsd, ws);
        mae_stage2<false><<<1, 256, 0, stream>>>(ws, outv);
    } else {
        // Fallback: 8 KB accumulator + atomics (deterministic; ws_size is fixed).
        hipMemsetAsync(ws, 0, N_DIM * 32 * sizeof(float), stream);
        mae_stage1<true><<<NBLOCKS, THREADS, 0, stream>>>(out_rsd, tgt_rsd, ws);
        mae_stage2<true><<<1, 256, 0, stream>>>(ws, outv);
    }
}

// Round 12
// 32.249 us; speedup vs baseline: 7.3873x; 1.0994x over previous
//
#include <hip/hip_runtime.h>
#include <math.h>

// Problem constants (fixed by the reference)
#define H_VAL   7500.0f
#define EH_VAL  750.0f          // 0.1f * 7500.0f, fp32-exact
#define N_DIM   64
#define T_DIM   65536
#define BLOCKS_PER_N 32
#define NBLOCKS (N_DIM * BLOCKS_PER_N)       // 2048 = 8 blocks/CU resident
#define THREADS 256
#define T_PER_BLOCK (T_DIM / BLOCKS_PER_N)   // 2048
#define ITERS (T_PER_BLOCK / THREADS)        // 8

// Native clang vector type: __builtin_nontemporal_load accepts this
// (it rejects HIP_vector_type<float,4>, R11 compile failure).
typedef float __attribute__((ext_vector_type(4))) f32x4;

__device__ __forceinline__ float dev_nan() { return __uint_as_float(0x7fc00000u); }
__device__ __forceinline__ bool is_nan(float x) { return x != x; }

// Statistics per (n,c), k = 0..6: {sum_all, sum_o, sum_u, sum_e, cnt_o, cnt_u, cnt_e}
// Partials mode (R4 layout): ws[block*28 + (0..15 sums: c*4+k | 16..27 counts: 16+f*4+c)]
// Atomic fallback: ws[n*32 + c*8 + (0..3 sums | 4..6 counts)], memset first.

template <bool ATOMIC>
__global__ __launch_bounds__(THREADS) void mae_stage1(
        const float* __restrict__ outp, const float* __restrict__ tgtp,
        float* __restrict__ ws) {
    const int bid = blockIdx.x;
    const int n = bid / BLOCKS_PER_N;
    const int slice = bid % BLOCKS_PER_N;
    const int t0 = slice * T_PER_BLOCK;
    const int tid = threadIdx.x;
    const int lane = tid & 63;
    const float h = H_VAL;
    const float eh = EH_VAL;

    // 16 per-lane float sums: w[c*4 + {0:all,1:o,2:u,3:e}]
    float w[16];
    #pragma unroll
    for (int i = 0; i < 16; ++i) w[i] = 0.0f;
    // 4 packed u32 counters/lane: bits 0-9 cnt_o, 10-19 cnt_u, 20-29 cnt_e
    unsigned cnt[4] = {0u, 0u, 0u, 0u};

    const f32x4* o4 = reinterpret_cast<const f32x4*>(outp) + (size_t)n * T_DIM;
    const f32x4* t4 = reinterpret_cast<const f32x4*>(tgtp) + (size_t)n * T_DIM;

    auto proc = [&](const f32x4& ov, const f32x4& tv) {
        const float os[4] = {ov.x, ov.y, ov.z, ov.w};
        const float ts[4] = {tv.x, tv.y, tv.z, tv.w};
        #pragma unroll
        for (int c = 0; c < 4; ++c) {
            const float traw = ts[c];
            const bool bo = (traw >= h) || (traw < 0.0f);  // == (tc==h)
            const float tc = bo ? h : traw;
            const float d = fabsf(os[c] - tc);
            const bool bu = (traw == 0.0f);
            const bool be = (traw > 0.0f) && (traw < eh);
            w[c * 4 + 0] += d;
            w[c * 4 + 1] += bo ? d : 0.0f;
            w[c * 4 + 2] += bu ? d : 0.0f;
            w[c * 4 + 3] += be ? d : 0.0f;
            cnt[c] += (bo ? 1u : 0u) + (bu ? (1u << 10) : 0u) + (be ? (1u << 20) : 0u);
        }
    };

    // Non-temporal (nt) 16B loads: read-once stream, bypass L1 allocation ->
    // misses are not bounded by the per-CU L1 MSHR pool (the R4-R10 ~4.5 TB/s
    // convergence point). Loop shape is R4's (compiles lean, VGPR ~32).
#define IDX(i) ((size_t)(t0 + (i) * THREADS + tid))
#define NTLD(p) __builtin_nontemporal_load(p)
    f32x4 a0o = NTLD(&o4[IDX(0)]), a1o = NTLD(&o4[IDX(1)]);
    f32x4 a0t = NTLD(&t4[IDX(0)]), a1t = NTLD(&t4[IDX(1)]);
    #pragma unroll
    for (int it = 0; it < ITERS; it += 2) {
        f32x4 b0o = a0o, b1o = a1o, b0t = a0t, b1t = a1t;
        if (it + 2 < ITERS) {
            b0o = NTLD(&o4[IDX(it + 2)]); b1o = NTLD(&o4[IDX(it + 3)]);
            b0t = NTLD(&t4[IDX(it + 2)]); b1t = NTLD(&t4[IDX(it + 3)]);
        }
        proc(a0o, a0t);
        proc(a1o, a1t);
        a0o = b0o; a1o = b1o; a0t = b0t; a1t = b1t;
    }
#undef NTLD
#undef IDX

    // --- Split-butterfly: 16 sums across 64 lanes in 17 shuffles ---
    #pragma unroll
    for (int r = 0; r < 4; ++r) {
        const int dist = 1 << r;
        const bool hi = (lane >> r) & 1;
        const int c16 = 8 >> r;
        #pragma unroll
        for (int j = 0; j < c16; ++j) {
            const float send = hi ? w[j] : w[j + c16];
            const float recv = __shfl_xor(send, dist, 64);
            w[j] = (hi ? w[j + c16] : w[j]) + recv;
        }
    }
    w[0] += __shfl_xor(w[0], 16, 64);
    w[0] += __shfl_xor(w[0], 32, 64);
    const int l4 = lane & 15;
    const int slot = ((l4 & 1) << 3) | (((l4 >> 1) & 1) << 2) |
                     (((l4 >> 2) & 1) << 1) | ((l4 >> 3) & 1);

    // --- Packed counts: 4 slots across 64 lanes in 7 shuffles ---
    #pragma unroll
    for (int r = 0; r < 2; ++r) {
        const int dist = 1 << r;
        const bool hi = (lane >> r) & 1;
        const int c4 = 2 >> r;
        #pragma unroll
        for (int j = 0; j < c4; ++j) {
            const unsigned send = hi ? cnt[j] : cnt[j + c4];
            const unsigned recv = __shfl_xor(send, dist, 64);
            cnt[j] = (hi ? cnt[j + c4] : cnt[j]) + recv;
        }
    }
    cnt[0] += __shfl_xor(cnt[0], 4, 64);
    cnt[0] += __shfl_xor(cnt[0], 8, 64);
    cnt[0] += __shfl_xor(cnt[0], 16, 64);
    cnt[0] += __shfl_xor(cnt[0], 32, 64);
    const int slot2 = ((lane & 1) << 1) | ((lane >> 1) & 1);

    __shared__ float    lsum[4][16];
    __shared__ unsigned lcnt[4][4];
    const int wave = tid >> 6;
    if (lane < 16) lsum[wave][slot] = w[0];
    if (lane < 4)  lcnt[wave][slot2] = cnt[0];
    __syncthreads();

    if (tid < 16) {
        const float s = lsum[0][tid] + lsum[1][tid] + lsum[2][tid] + lsum[3][tid];
        const int c = tid >> 2, k = tid & 3;
        if (ATOMIC) atomicAdd(&ws[n * 32 + c * 8 + k], s);
        else        ws[bid * 28 + tid] = s;
    } else if (tid < 28) {
        const int j = tid - 16, f = j >> 2, c = j & 3;
        const unsigned v = ((lcnt[0][c] >> (10 * f)) & 1023u) +
                           ((lcnt[1][c] >> (10 * f)) & 1023u) +
                           ((lcnt[2][c] >> (10 * f)) & 1023u) +
                           ((lcnt[3][c] >> (10 * f)) & 1023u);
        const float fv = (float)v;
        if (ATOMIC) atomicAdd(&ws[n * 32 + c * 8 + 4 + f], fv);
        else        ws[bid * 28 + tid] = fv;
    }
}

template <bool ATOMIC>
__global__ __launch_bounds__(256) void mae_stage2(
        const float* __restrict__ ws, float* __restrict__ outp) {
    const int i = threadIdx.x;            // 0..255 == (n,c) pair
    const int n = i >> 2, c = i & 3;

    float a[7];
    if (ATOMIC) {
        const float* p = &ws[n * 32 + c * 8];
        #pragma unroll
        for (int k = 0; k < 7; ++k) a[k] = p[k];
    } else {
        #pragma unroll
        for (int k = 0; k < 7; ++k) a[k] = 0.0f;
        for (int s = 0; s < BLOCKS_PER_N; ++s) {
            const float* p = &ws[(size_t)(n * BLOCKS_PER_N + s) * 28];
            #pragma unroll
            for (int k = 0; k < 4; ++k) a[k] += p[c * 4 + k];
            #pragma unroll
            for (int f = 0; f < 3; ++f) a[4 + f] += p[16 + f * 4 + c];
        }
    }

    const float sum_all = a[0], sum_o = a[1], sum_u = a[2], sum_e = a[3];
    const float cnt_o = a[4], cnt_u = a[5], cnt_e = a[6];
    const float cnt_in = (float)T_DIM - cnt_o - cnt_u;   // exact in fp32
    const float sum_in = sum_all - sum_o - sum_u;

    const float m_o  = (cnt_o  > 0.0f) ? sum_o  / cnt_o  : dev_nan();
    const float m_in = (cnt_in > 0.0f) ? sum_in / cnt_in : dev_nan();
    const float m_u  = (cnt_u  > 0.0f) ? sum_u  / cnt_u  : dev_nan();
    const float m_e  = (cnt_e  > 0.0f) ? sum_e  / cnt_e  : dev_nan();

    auto nm2 = [](float x, float y) {
        const bool vx = !is_nan(x), vy = !is_nan(y);
        const float s  = (vx ? x : 0.0f) + (vy ? y : 0.0f);
        const float cc = (vx ? 1.0f : 0.0f) + (vy ? 1.0f : 0.0f);
        return (cc > 0.0f) ? s / cc : dev_nan();
    };
    const float in_comb = nm2(m_u, m_in);
    const float wv      = nm2(m_o, in_comb);

    float vals[4] = {wv, in_comb, m_o, m_e};   // -> wMAE, inMAE, oMAE, eMAE
    float sums[4], cnts[4];
    #pragma unroll
    for (int j = 0; j < 4; ++j) {
        const bool valid = !is_nan(vals[j]);
        sums[j] = valid ? vals[j] : 0.0f;
        cnts[j] = valid ? 1.0f : 0.0f;
    }
    #pragma unroll
    for (int j = 0; j < 4; ++j) {
        #pragma unroll
        for (int off = 32; off > 0; off >>= 1) {
            sums[j] += __shfl_down(sums[j], off, 64);
            cnts[j] += __shfl_down(cnts[j], off, 64);
        }
    }
    __shared__ float ls[4][8];
    const int wave = threadIdx.x >> 6;
    const int lane = threadIdx.x & 63;
    if (lane == 0) {
        #pragma unroll
        for (int j = 0; j < 4; ++j) { ls[wave][j] = sums[j]; ls[wave][j + 4] = cnts[j]; }
    }
    __syncthreads();
    if (threadIdx.x == 0) {
        #pragma unroll
        for (int j = 0; j < 4; ++j) {
            const float s  = ls[0][j] + ls[1][j] + ls[2][j] + ls[3][j];
            const float cc = ls[0][j + 4] + ls[1][j + 4] + ls[2][j + 4] + ls[3][j + 4];
            outp[j] = (cc > 0.0f) ? s / cc : dev_nan();
        }
    }
}

extern "C" void kernel_launch(void* const* d_in, const int* in_sizes, int n_in,
                              void* d_out, int out_size, void* d_ws, size_t ws_size,
                              hipStream_t stream) {
    const float* out_rsd = (const float*)d_in[0];
    const float* tgt_rsd = (const float*)d_in[1];
    float* outv = (float*)d_out;
    float* ws = (float*)d_ws;

    const size_t partials_bytes = (size_t)NBLOCKS * 28 * sizeof(float);
    if (ws_size >= partials_bytes) {
        // No memset, no atomics: every partial slot is written unconditionally.
        mae_stage1<false><<<NBLOCKS, THREADS, 0, stream>>>(out_rsd, tgt_rsd, ws);
        mae_stage2<false><<<1, 256, 0, stream>>>(ws, outv);
    } else {
        // Fallback: 8 KB accumulator + atomics (deterministic; ws_size is fixed).
        hipError_t e = hipMemsetAsync(ws, 0, N_DIM * 32 * sizeof(float), stream);
        (void)e;
        mae_stage1<true><<<NBLOCKS, THREADS, 0, stream>>>(out_rsd, tgt_rsd, ws);
        mae_stage2<true><<<1, 256, 0, stream>>>(ws, outv);
    }
}